// Round 1
// baseline (233.385 us; speedup 1.0000x reference)
//
#include <hip/hip_runtime.h>
#include <hip/hip_bf16.h>
#include <cstdint>
#include <cstddef>

typedef __attribute__((ext_vector_type(8))) _Float16 half8;
typedef __attribute__((ext_vector_type(4))) float f32x4;
typedef __attribute__((ext_vector_type(8))) unsigned short ushort8v;
typedef __attribute__((ext_vector_type(4))) unsigned short ushort4v;

__device__ __forceinline__ unsigned short f2h_bits(float x) {
  _Float16 h = (_Float16)x;
  union { _Float16 h; unsigned short u; } cv; cv.h = h; return cv.u;
}
__device__ __forceinline__ float h2f(unsigned short u) {
  union { _Float16 h; unsigned short u; } cv; cv.u = u; return (float)cv.h;
}

// ---------------- prep kernels ----------------

__global__ __launch_bounds__(256) void k_f32_to_f16(const float* __restrict__ src,
                                                    unsigned short* __restrict__ dst, int n4) {
  int i = blockIdx.x * 256 + threadIdx.x;
  if (i >= n4) return;
  float4 v = ((const float4*)src)[i];
  ushort4v o;
  o[0] = f2h_bits(v.x); o[1] = f2h_bits(v.y); o[2] = f2h_bits(v.z); o[3] = f2h_bits(v.w);
  ((ushort4v*)dst)[i] = o;
}

// W [Kd][N] fp32 (row-major) -> Wt rows [rowOff+n][Kd] fp16
__global__ __launch_bounds__(256) void k_transpose_f16(const float* __restrict__ W,
                                                       unsigned short* __restrict__ Wt,
                                                       int Kd, int N, int rowOff) {
  int tid = blockIdx.x * 256 + threadIdx.x;
  int total = (Kd >> 3) * N;
  if (tid >= total) return;
  int kc = tid / N;
  int n  = tid - kc * N;
  int k0 = kc << 3;
  ushort8v o;
#pragma unroll
  for (int j = 0; j < 8; ++j) o[j] = f2h_bits(W[(size_t)(k0 + j) * N + n]);
  *(ushort8v*)(&Wt[(size_t)(rowOff + n) * Kd + k0]) = o;
}

__global__ __launch_bounds__(256) void k_zero_u16(unsigned short* p, int n) {
  int i = blockIdx.x * 256 + threadIdx.x;
  if (i < n) p[i] = 0;
}

__global__ __launch_bounds__(256) void k_zero_f32x4(float4* p, int n4) {
  int i = blockIdx.x * 256 + threadIdx.x;
  if (i < n4) p[i] = make_float4(0.f, 0.f, 0.f, 0.f);
}

// ---------------- MFMA GEMM (m97-style 128x128 tile) ----------------
// A: [M][Kd] fp16.  Bt: [N][Kd] fp16 (i.e. original W transposed).
// EPI 0: Hout[row*N+col] = fp16(relu(acc+bias[col]))
// EPI 1: head epilogue (mu + tril scatter with exp on diagonal)

template<int EPI>
__global__ __launch_bounds__(256) void k_gemm128(
    const unsigned short* __restrict__ A,
    const unsigned short* __restrict__ Bt,
    int Kd, int N,
    const float* __restrict__ bias,
    unsigned short* __restrict__ Hout,
    const float* __restrict__ bmu,
    const float* __restrict__ btl,
    float* __restrict__ out_mu,
    float* __restrict__ out_tril)
{
  __shared__ unsigned short Alds[128 * 32];
  __shared__ unsigned short Blds[128 * 32];

  const int tid  = threadIdx.x;
  const int lane = tid & 63;
  const int wv   = tid >> 6;     // wave 0..3
  const int wr   = wv >> 1;      // wave row 0..1
  const int wc   = wv & 1;       // wave col 0..1
  const int bm   = blockIdx.x << 7;
  const int bn   = blockIdx.y << 7;

  f32x4 acc[4][4] = {};

  const int l15  = lane & 15;
  const int lk   = lane >> 4;          // k-group 0..3
  const int srow = lane >> 2;          // staging row-in-chunk 0..15
  const int scol = (lane & 3) << 3;    // staging elem offset 0/8/16/24

  const unsigned short* aBase = A  + (size_t)bm * Kd;
  const unsigned short* bBase = Bt + (size_t)bn * Kd;

  const int nk = Kd >> 5;
  for (int kt = 0; kt < nk; ++kt) {
    const int k0 = kt << 5;
    // stage: each wave moves 2 KB of A + 2 KB of B (16B per lane per call)
#pragma unroll
    for (int c = 0; c < 2; ++c) {
      const int chunk = wv * 2 + c;           // 0..7
      const int row = (chunk << 4) + srow;    // 0..127
      __builtin_amdgcn_global_load_lds(
          (const __attribute__((address_space(1))) void*)(aBase + (size_t)row * Kd + k0 + scol),
          (__attribute__((address_space(3))) void*)(Alds + (chunk << 9)),
          16, 0, 0);
      __builtin_amdgcn_global_load_lds(
          (const __attribute__((address_space(1))) void*)(bBase + (size_t)row * Kd + k0 + scol),
          (__attribute__((address_space(3))) void*)(Blds + (chunk << 9)),
          16, 0, 0);
    }
    __syncthreads();   // drains vmcnt before barrier (compiler-inserted)

    const unsigned short* al = Alds + ((wr << 6) + l15) * 32 + (lk << 3);
    const unsigned short* bl = Blds + ((wc << 6) + l15) * 32 + (lk << 3);
    half8 af[4], bfr[4];
#pragma unroll
    for (int m = 0; m < 4; ++m) af[m]  = *(const half8*)(al + (m << 9));
#pragma unroll
    for (int n = 0; n < 4; ++n) bfr[n] = *(const half8*)(bl + (n << 9));
#pragma unroll
    for (int m = 0; m < 4; ++m)
#pragma unroll
      for (int n = 0; n < 4; ++n)
        acc[m][n] = __builtin_amdgcn_mfma_f32_16x16x32_f16(af[m], bfr[n], acc[m][n], 0, 0, 0);
    __syncthreads();   // protect LDS from next iteration's staging
  }

  // epilogue: C row = bm + wr*64 + m*16 + lk*4 + r ; col = bn + wc*64 + n*16 + l15
  const int orow = bm + (wr << 6) + (lk << 2);
#pragma unroll
  for (int m = 0; m < 4; ++m) {
#pragma unroll
    for (int n = 0; n < 4; ++n) {
      const int col = bn + (wc << 6) + (n << 4) + l15;
#pragma unroll
      for (int r = 0; r < 4; ++r) {
        const int row = orow + (m << 4) + r;
        float v = acc[m][n][r];
        if (EPI == 0) {
          v += bias[col];
          v = v > 0.f ? v : 0.f;
          Hout[(size_t)row * N + col] = f2h_bits(v);
        } else {
          if (col < 128) {
            out_mu[(size_t)row * 128 + col] = v + bmu[col];
          } else if (col < 1216) {
            const int cc = col - 128;
            const int k  = cc / 136;
            const int t  = cc - k * 136;
            float vv = v + btl[cc];
            int i = (int)((sqrtf(8.f * (float)t + 1.f) - 1.f) * 0.5f);
            if ((i + 1) * (i + 2) / 2 <= t) ++i;
            if (i * (i + 1) / 2 > t) --i;
            const int j = t - ((i * (i + 1)) >> 1);
            if (i == j) vv = expf(vv);
            out_tril[((size_t)row << 11) + (k << 8) + (i << 4) + j] = vv;
          }
          // col >= 1216: padding, discard
        }
      }
    }
  }
}

// ---------------- pi head: GEMV + softmax over K=8 ----------------
__global__ __launch_bounds__(256) void k_pi(const unsigned short* __restrict__ h2,
                                            const float* __restrict__ Wpi,
                                            const float* __restrict__ bpi,
                                            float* __restrict__ out_pi)
{
  const int tid = threadIdx.x;
  const int k   = tid & 7;
  const int r8  = tid >> 3;                   // 0..31
  const int row = blockIdx.x * 32 + r8;
  const unsigned short* hrow = h2 + ((size_t)row << 9);
  float acc = 0.f;
  for (int d = 0; d < 512; d += 4) {
    ushort4v hv = *(const ushort4v*)(hrow + d);
#pragma unroll
    for (int j = 0; j < 4; ++j) acc += h2f(hv[j]) * Wpi[(d + j) * 8 + k];
  }
  acc += bpi[k];
  float mx = acc;
#pragma unroll
  for (int s = 1; s < 8; s <<= 1) mx = fmaxf(mx, __shfl_xor(mx, s));
  float e = expf(acc - mx);
  float sm = e;
#pragma unroll
  for (int s = 1; s < 8; s <<= 1) sm += __shfl_xor(sm, s);
  out_pi[((size_t)row << 3) + k] = e / sm;
}

// ---------------- launch ----------------

extern "C" void kernel_launch(void* const* d_in, const int* in_sizes, int n_in,
                              void* d_out, int out_size, void* d_ws, size_t ws_size,
                              hipStream_t stream)
{
  const float* x   = (const float*)d_in[0];
  const float* W0  = (const float*)d_in[1];
  const float* b0  = (const float*)d_in[2];
  const float* W1  = (const float*)d_in[3];
  const float* b1  = (const float*)d_in[4];
  const float* W2  = (const float*)d_in[5];
  const float* b2  = (const float*)d_in[6];
  const float* Wpi = (const float*)d_in[7];
  const float* bpi = (const float*)d_in[8];
  const float* Wmu = (const float*)d_in[9];
  const float* bmu = (const float*)d_in[10];
  const float* Wt  = (const float*)d_in[11];
  const float* bt  = (const float*)d_in[12];

  char* ws = (char*)d_ws;
  unsigned short* xh  = (unsigned short*)(ws);             //  8,388,608 B
  unsigned short* h0  = (unsigned short*)(ws + 8388608);   // 33,554,432 B
  unsigned short* h1  = (unsigned short*)(ws + 41943040);  // 33,554,432 B
  unsigned short* h2  = (unsigned short*)(ws + 75497472);  // 16,777,216 B
  unsigned short* w0b = (unsigned short*)(ws + 92274688);  //    524,288 B [1024][256]
  unsigned short* w1b = (unsigned short*)(ws + 92798976);  //  2,097,152 B [1024][1024]
  unsigned short* w2b = (unsigned short*)(ws + 94896128);  //  1,048,576 B [512][1024]
  unsigned short* wmt = (unsigned short*)(ws + 95944704);  //  1,310,720 B [1280][512]

  float* out_pi   = (float*)d_out;                // 131072
  float* out_mu   = (float*)d_out + 131072;       // 2097152
  float* out_tril = (float*)d_out + 2228224;      // 33554432

  // prep: dtype conversion + weight transpose (+ pad), zero tril region
  k_f32_to_f16<<<4096, 256, 0, stream>>>(x, xh, 1048576);
  k_transpose_f16<<<128, 256, 0, stream>>>(W0, w0b, 256, 1024, 0);
  k_transpose_f16<<<512, 256, 0, stream>>>(W1, w1b, 1024, 1024, 0);
  k_transpose_f16<<<256, 256, 0, stream>>>(W2, w2b, 1024, 512, 0);
  k_transpose_f16<<<32, 256, 0, stream>>>(Wmu, wmt, 512, 128, 0);
  k_transpose_f16<<<272, 256, 0, stream>>>(Wt, wmt, 512, 1088, 128);
  k_zero_u16<<<128, 256, 0, stream>>>(wmt + (size_t)1216 * 512, 32768);
  k_zero_f32x4<<<32768, 256, 0, stream>>>((float4*)out_tril, 8388608);

  // trunk GEMMs (M=16384)
  k_gemm128<0><<<dim3(128, 8),  256, 0, stream>>>(xh, w0b, 256, 1024, b0, h0,
                                                  nullptr, nullptr, nullptr, nullptr);
  k_gemm128<0><<<dim3(128, 8),  256, 0, stream>>>(h0, w1b, 1024, 1024, b1, h1,
                                                  nullptr, nullptr, nullptr, nullptr);
  k_gemm128<0><<<dim3(128, 4),  256, 0, stream>>>(h1, w2b, 1024, 512, b2, h2,
                                                  nullptr, nullptr, nullptr, nullptr);
  // heads: mu + tril (N padded 1224 -> 1280)
  k_gemm128<1><<<dim3(128, 10), 256, 0, stream>>>(h2, wmt, 512, 1280, nullptr, nullptr,
                                                  bmu, bt, out_mu, out_tril);
  k_pi<<<512, 256, 0, stream>>>(h2, Wpi, bpi, out_pi);
}

// Round 2
// 191.311 us; speedup vs baseline: 1.2199x; 1.2199x over previous
//
#include <hip/hip_runtime.h>
#include <hip/hip_bf16.h>
#include <cstdint>
#include <cstddef>

typedef __attribute__((ext_vector_type(8))) _Float16 half8;
typedef __attribute__((ext_vector_type(4))) float f32x4;
typedef __attribute__((ext_vector_type(8))) unsigned short ushort8v;
typedef __attribute__((ext_vector_type(4))) unsigned short ushort4v;

__device__ __forceinline__ unsigned short f2h_bits(float x) {
  _Float16 h = (_Float16)x;
  union { _Float16 h; unsigned short u; } cv; cv.h = h; return cv.u;
}

// ---------------- prep kernels ----------------

__global__ __launch_bounds__(256) void k_f32_to_f16(const float* __restrict__ src,
                                                    unsigned short* __restrict__ dst, int n4) {
  int i = blockIdx.x * 256 + threadIdx.x;
  if (i >= n4) return;
  float4 v = ((const float4*)src)[i];
  ushort4v o;
  o[0] = f2h_bits(v.x); o[1] = f2h_bits(v.y); o[2] = f2h_bits(v.z); o[3] = f2h_bits(v.w);
  ((ushort4v*)dst)[i] = o;
}

// W [Kd][N] fp32 (row-major) -> Wt rows [n][Kd] fp16
__global__ __launch_bounds__(256) void k_transpose_f16(const float* __restrict__ W,
                                                       unsigned short* __restrict__ Wt,
                                                       int Kd, int N) {
  int tid = blockIdx.x * 256 + threadIdx.x;
  int total = (Kd >> 3) * N;
  if (tid >= total) return;
  int kc = tid / N;
  int n  = tid - kc * N;
  int k0 = kc << 3;
  ushort8v o;
#pragma unroll
  for (int j = 0; j < 8; ++j) o[j] = f2h_bits(W[(size_t)(k0 + j) * N + n]);
  *(ushort8v*)(&Wt[(size_t)n * Kd + k0]) = o;
}

// Build unpacked head weight whd [2304][512] fp16 and bias bhd [2304] f32.
// rows 0..127: mu; 128..2175: tril unpacked (k*256+i*16+j, zero if j>i);
// 2176..2183: pi; 2184..2303: zero pad.
__global__ __launch_bounds__(256) void k_build_head(
    const float* __restrict__ Wmu, const float* __restrict__ Wt,
    const float* __restrict__ Wpi,
    const float* __restrict__ bmu, const float* __restrict__ bt,
    const float* __restrict__ bpi,
    unsigned short* __restrict__ whd, float* __restrict__ bhd)
{
  int tid = blockIdx.x * 256 + threadIdx.x;   // (r, d-chunk of 8): 2304*64
  if (tid >= 2304 * 64) return;
  int r  = tid >> 6;
  int d0 = (tid & 63) << 3;

  const float* src = nullptr; int stride = 0;
  if (r < 128) { src = Wmu + r; stride = 128; }
  else if (r < 2176) {
    int rU = r - 128, k = rU >> 8, i = (rU >> 4) & 15, j = rU & 15;
    if (j <= i) { src = Wt + k * 136 + ((i * (i + 1)) >> 1) + j; stride = 1088; }
  } else if (r < 2184) { src = Wpi + (r - 2176); stride = 8; }

  ushort8v o;
#pragma unroll
  for (int jj = 0; jj < 8; ++jj)
    o[jj] = src ? f2h_bits(src[(size_t)(d0 + jj) * stride]) : (unsigned short)0;
  *(ushort8v*)(&whd[(size_t)r * 512 + d0]) = o;

  if (d0 == 0) {
    float b = 0.f;
    if (r < 128) b = bmu[r];
    else if (r < 2176) {
      int rU = r - 128, k = rU >> 8, i = (rU >> 4) & 15, j = rU & 15;
      if (j <= i) b = bt[k * 136 + ((i * (i + 1)) >> 1) + j];
    } else if (r < 2184) b = bpi[r - 2176];
    bhd[r] = b;
  }
}

// ---------------- MFMA GEMM: 128x128 tile, 2-phase double-buffered ----------------
// A: [M][Kd] fp16.  Bt: [N][Kd] fp16.
// EPI 0: Hout[row*N+col] = fp16(relu(acc+bias[col]))
// EPI 1: head epilogue (mu / tril-with-exp-diag / pi-softmax), bias = bhd

template<int EPI>
__global__ __launch_bounds__(256) void k_gemm128(
    const unsigned short* __restrict__ A,
    const unsigned short* __restrict__ Bt,
    int Kd, int N,
    const float* __restrict__ bias,
    unsigned short* __restrict__ Hout,
    float* __restrict__ out_pi,
    float* __restrict__ out_mu,
    float* __restrict__ out_tril)
{
  __shared__ unsigned short Alds[2][128 * 32];
  __shared__ unsigned short Blds[2][128 * 32];

  const int tid  = threadIdx.x;
  const int lane = tid & 63;
  const int wv   = tid >> 6;     // wave 0..3
  const int wr   = wv >> 1;      // wave row 0..1
  const int wc   = wv & 1;       // wave col 0..1
  const int bm   = blockIdx.x << 7;
  const int bn   = blockIdx.y << 7;

  f32x4 acc[4][4] = {};

  const int l15  = lane & 15;
  const int lk   = lane >> 4;          // k-group 0..3
  const int srow = lane >> 2;          // staging row-in-chunk 0..15
  const int scol = (lane & 3) << 3;    // staging elem offset 0/8/16/24

  const unsigned short* aBase = A  + (size_t)bm * Kd;
  const unsigned short* bBase = Bt + (size_t)bn * Kd;

  auto stage = [&](int bb, int k0) {
#pragma unroll
    for (int c = 0; c < 2; ++c) {
      const int chunk = (wv << 1) + c;        // 0..7
      const int row = (chunk << 4) + srow;    // 0..127
      __builtin_amdgcn_global_load_lds(
          (const __attribute__((address_space(1))) void*)(aBase + (size_t)row * Kd + k0 + scol),
          (__attribute__((address_space(3))) void*)(&Alds[bb][chunk << 9]),
          16, 0, 0);
      __builtin_amdgcn_global_load_lds(
          (const __attribute__((address_space(1))) void*)(bBase + (size_t)row * Kd + k0 + scol),
          (__attribute__((address_space(3))) void*)(&Blds[bb][chunk << 9]),
          16, 0, 0);
    }
  };

  const int nk = Kd >> 5;
  stage(0, 0);
  __syncthreads();          // compiler drains vmcnt(0) before s_barrier
  int cur = 0;
  for (int kt = 0; kt < nk; ++kt) {
    if (kt + 1 < nk) stage(cur ^ 1, (kt + 1) << 5);   // prefetch overlaps MFMA below

    const unsigned short* al = &Alds[cur][((wr << 6) + l15) * 32 + (lk << 3)];
    const unsigned short* bl = &Blds[cur][((wc << 6) + l15) * 32 + (lk << 3)];
    half8 af[4], bfr[4];
#pragma unroll
    for (int m = 0; m < 4; ++m) af[m]  = *(const half8*)(al + (m << 9));
#pragma unroll
    for (int n = 0; n < 4; ++n) bfr[n] = *(const half8*)(bl + (n << 9));
#pragma unroll
    for (int m = 0; m < 4; ++m)
#pragma unroll
      for (int n = 0; n < 4; ++n)
        acc[m][n] = __builtin_amdgcn_mfma_f32_16x16x32_f16(af[m], bfr[n], acc[m][n], 0, 0, 0);

    __syncthreads();        // drains prefetch vmcnt + protects LDS reuse
    cur ^= 1;
  }

  // epilogue: C row = bm + wr*64 + m*16 + lk*4 + r ; col = bn + wc*64 + n*16 + l15
  const int orow = bm + (wr << 6) + (lk << 2);
#pragma unroll
  for (int m = 0; m < 4; ++m) {
#pragma unroll
    for (int n = 0; n < 4; ++n) {
      const int col = bn + (wc << 6) + (n << 4) + l15;
#pragma unroll
      for (int r = 0; r < 4; ++r) {
        const int row = orow + (m << 4) + r;
        if (EPI == 0) {
          float v = acc[m][n][r] + bias[col];
          v = v > 0.f ? v : 0.f;
          Hout[(size_t)row * N + col] = f2h_bits(v);
        } else {
          float v = acc[m][n][r] + bias[col];
          if (col < 128) {
            out_mu[(size_t)row * 128 + col] = v;
          } else if (col < 2176) {
            const int cc = col - 128;
            if (((cc >> 4) & 15) == (cc & 15)) v = expf(v);   // diagonal
            out_tril[(size_t)row * 2048 + cc] = v;            // zeros for j>i fall out
          } else if (col < 2184) {
            float mx = v;
#pragma unroll
            for (int s = 1; s < 8; s <<= 1) mx = fmaxf(mx, __shfl_xor(mx, s));
            float e = expf(v - mx);
            float sm = e;
#pragma unroll
            for (int s = 1; s < 8; s <<= 1) sm += __shfl_xor(sm, s);
            out_pi[((size_t)row << 3) + (col - 2176)] = e / sm;
          }
          // col >= 2184: padding, discard
        }
      }
    }
  }
}

// ---------------- launch ----------------

extern "C" void kernel_launch(void* const* d_in, const int* in_sizes, int n_in,
                              void* d_out, int out_size, void* d_ws, size_t ws_size,
                              hipStream_t stream)
{
  const float* x   = (const float*)d_in[0];
  const float* W0  = (const float*)d_in[1];
  const float* b0  = (const float*)d_in[2];
  const float* W1  = (const float*)d_in[3];
  const float* b1  = (const float*)d_in[4];
  const float* W2  = (const float*)d_in[5];
  const float* b2  = (const float*)d_in[6];
  const float* Wpi = (const float*)d_in[7];
  const float* bpi = (const float*)d_in[8];
  const float* Wmu = (const float*)d_in[9];
  const float* bmu = (const float*)d_in[10];
  const float* Wt  = (const float*)d_in[11];
  const float* bt  = (const float*)d_in[12];

  char* ws = (char*)d_ws;
  unsigned short* xh  = (unsigned short*)(ws);             //  8,388,608 B
  unsigned short* h0  = (unsigned short*)(ws + 8388608);   // 33,554,432 B
  unsigned short* h1  = (unsigned short*)(ws + 41943040);  // 33,554,432 B
  unsigned short* h2  = (unsigned short*)(ws + 8388608);   // 16,777,216 B (aliases h0 — dead by then)
  unsigned short* w0b = (unsigned short*)(ws + 75497472);  //    524,288 B [1024][256]
  unsigned short* w1b = (unsigned short*)(ws + 76021760);  //  2,097,152 B [1024][1024]
  unsigned short* w2b = (unsigned short*)(ws + 78118912);  //  1,048,576 B [512][1024]
  unsigned short* whd = (unsigned short*)(ws + 79167488);  //  2,359,296 B [2304][512]
  float*          bhd = (float*)         (ws + 81526784);  //      9,216 B [2304]

  float* out_pi   = (float*)d_out;                // 131072
  float* out_mu   = (float*)d_out + 131072;       // 2097152
  float* out_tril = (float*)d_out + 2228224;      // 33554432

  // prep
  k_f32_to_f16<<<4096, 256, 0, stream>>>(x, xh, 1048576);
  k_transpose_f16<<<128, 256, 0, stream>>>(W0, w0b, 256, 1024);
  k_transpose_f16<<<512, 256, 0, stream>>>(W1, w1b, 1024, 1024);
  k_transpose_f16<<<256, 256, 0, stream>>>(W2, w2b, 1024, 512);
  k_build_head<<<576, 256, 0, stream>>>(Wmu, Wt, Wpi, bmu, bt, bpi, whd, bhd);

  // trunk GEMMs (M=16384)
  k_gemm128<0><<<dim3(128, 8),  256, 0, stream>>>(xh, w0b, 256, 1024, b0, h0,
                                                  nullptr, nullptr, nullptr);
  k_gemm128<0><<<dim3(128, 8),  256, 0, stream>>>(h0, w1b, 1024, 1024, b1, h1,
                                                  nullptr, nullptr, nullptr);
  k_gemm128<0><<<dim3(128, 4),  256, 0, stream>>>(h1, w2b, 1024, 512, b2, h2,
                                                  nullptr, nullptr, nullptr);
  // heads: mu + tril + pi in one GEMM (N = 2304: 128 mu | 2048 tril | 8 pi | 120 pad)
  k_gemm128<1><<<dim3(128, 18), 256, 0, stream>>>(h2, whd, 512, 2304, bhd, nullptr,
                                                  out_pi, out_mu, out_tril);
}